// Round 2
// baseline (125.304 us; speedup 1.0000x reference)
//
#include <hip/hip_runtime.h>

// CanadarmJacob: 131072 independent items, each:
//   rot(3x7) from pose columns AXIS_LIST={2,0,2,2,2,0,2} (col 4 negated)
//   del_p = com - trans; jt = rot x del_p
//   H_s (sym 3x3) inverse; per-column small algebra -> out (6x7)
// Memory-bound: ~92MB effective traffic -> target ~15-25us.

__global__ __launch_bounds__(256) void canadarm_jacob_kernel(
    const float* __restrict__ com,
    const float* __restrict__ pose,
    const int* __restrict__ bm_ptr,
    float* __restrict__ out,
    int n_items)
{
    const int idx = blockIdx.x * blockDim.x + threadIdx.x;
    if (idx >= n_items) return;

    // ---- compile-time constants (match reference f32 values) ----
    const float MASS[7] = {105.98f, 105.98f, 314.98f, 279.2f, 105.98f, 105.98f, 243.66f};
    // suffix sums of MASS
    const float SUMM[7] = {1261.76f, 1155.78f, 1049.80f, 734.82f, 455.62f, 349.64f, 243.66f};
    // suffix sums of DIAGS columns (SUM_INERTIAL diagonals)
    const float SIX[7] = {79.083f, 66.893f, 54.703f, 39.293f, 29.771f, 21.466f, 9.336f};
    const float SIY[7] = {4144.971f, 4132.781f, 4120.591f, 2025.881f, 59.601f, 56.540f, 44.410f};
    const float SIZ[7] = {4131.1016f, 4128.0406f, 4124.9796f, 2021.7896f, 55.5096f, 47.471f, 44.410f};
    const float TM     = 101505.42f;                       // TOTAL_MASS
    const float INV_TM = 1.0f / 101505.42f;
    const float BCZ    = 6.65f * 243.66f / 100243.66f;     // BASE_COM.z (x=y=0)

    // ---- load pose: 7 aligned float4 per matrix row ----
    // pose block per item: (4,4,9) floats = 144 floats, 576B (16B aligned)
    const float4* Pb = reinterpret_cast<const float4*>(pose) + (size_t)idx * 36;
    float rot[3][7];
    float tr[3][8];  // translations for links 0..7 (7 needed only for bm==0)
#pragma unroll
    for (int r = 0; r < 3; ++r) {
        // row r = floats [r*36, r*36+36); float4 indices r*9 + {0,1,4,5,6,7,8}
        const float4 q0 = Pb[r * 9 + 0];  // floats 0..3   (use idx1 = c0,l1)
        const float4 q1 = Pb[r * 9 + 1];  // floats 4..7   (use idx5 = c0,l5)
        const float4 q4 = Pb[r * 9 + 4];  // floats 16..19 (use idx18 = c2,l0)
        const float4 q5 = Pb[r * 9 + 5];  // floats 20..23 (idx20,21,22 = c2,l2/3/4)
        const float4 q6 = Pb[r * 9 + 6];  // floats 24..27 (idx24 = c2,l6; idx27 = c3,l0)
        const float4 q7 = Pb[r * 9 + 7];  // floats 28..31 (c3, l1..l4)
        const float4 q8 = Pb[r * 9 + 8];  // floats 32..35 (c3, l5..l7)
        rot[r][0] = q4.z;
        rot[r][1] = q0.y;
        rot[r][2] = q5.x;
        rot[r][3] = q5.y;
        rot[r][4] = -q5.z;   // ROT_SIGN[4] = -1
        rot[r][5] = q1.y;
        rot[r][6] = q6.x;
        tr[r][0] = q6.w;
        tr[r][1] = q7.x; tr[r][2] = q7.y; tr[r][3] = q7.z; tr[r][4] = q7.w;
        tr[r][5] = q8.x; tr[r][6] = q8.y; tr[r][7] = q8.z;
    }

    const int bm = bm_ptr[0];
    float o[42];

    if (bm) {
        // ---- load com (3,7) ----
        const float* C = com + (size_t)idx * 21;
        float cm[3][7];
#pragma unroll
        for (int r = 0; r < 3; ++r)
#pragma unroll
            for (int i = 0; i < 7; ++i) cm[r][i] = C[r * 7 + i];

        // system com -> v = system_com - BASE_COM
        float scx = 0.f, scy = 0.f, scz = 0.f;
#pragma unroll
        for (int i = 0; i < 7; ++i) {
            scx += cm[0][i] * MASS[i];
            scy += cm[1][i] * MASS[i];
            scz += cm[2][i] * MASS[i];
        }
        const float vx = scx * INV_TM;
        const float vy = scy * INV_TM;
        const float vz = scz * INV_TM - BCZ;

        // del_p, jacob_t, H_w accumulation
        float dp[3][7], jt[3][7];
        float hxx = SIX[0], hyy = SIY[0], hzz = SIZ[0];
        float hxy = 0.f, hxz = 0.f, hyz = 0.f;
#pragma unroll
        for (int i = 0; i < 7; ++i) {
            const float x = cm[0][i] - tr[0][i];
            const float y = cm[1][i] - tr[1][i];
            const float z = cm[2][i] - tr[2][i];
            dp[0][i] = x; dp[1][i] = y; dp[2][i] = z;
            jt[0][i] = rot[1][i] * z - rot[2][i] * y;
            jt[1][i] = rot[2][i] * x - rot[0][i] * z;
            jt[2][i] = rot[0][i] * y - rot[1][i] * x;
            const float m = MASS[i];
            hxx += m * (y * y + z * z);
            hyy += m * (x * x + z * z);
            hzz += m * (x * x + y * y);
            hxy -= m * x * y;
            hxz -= m * x * z;
            hyz -= m * y * z;
        }

        // suffix scan: wsum[k] = sum_{a>=k} MASS[a]*dp[:,a]
        float wx[7], wy[7], wz[7];
        wx[6] = MASS[6] * dp[0][6];
        wy[6] = MASS[6] * dp[1][6];
        wz[6] = MASS[6] * dp[2][6];
#pragma unroll
        for (int k = 5; k >= 0; --k) {
            wx[k] = wx[k + 1] + MASS[k] * dp[0][k];
            wy[k] = wy[k + 1] + MASS[k] * dp[1][k];
            wz[k] = wz[k + 1] + MASS[k] * dp[2][k];
        }

        // H_s = TM*(v v^T - (v.v) I) + H_w  (symmetric)
        const float vv = vx * vx + vy * vy + vz * vz;
        const float a  = hxx + TM * (vx * vx - vv);
        const float b  = hxy + TM * (vx * vy);
        const float c  = hxz + TM * (vx * vz);
        const float e  = hyy + TM * (vy * vy - vv);
        const float f  = hyz + TM * (vy * vz);
        const float i9 = hzz + TM * (vz * vz - vv);

        // symmetric 3x3 inverse
        const float c11 = e * i9 - f * f;
        const float c12 = c * f - b * i9;
        const float c13 = b * f - e * c;
        const float det = a * c11 + b * c12 + c * c13;
        const float rdet = 1.0f / det;
        const float i00 = c11 * rdet;
        const float i01 = c12 * rdet;
        const float i02 = c13 * rdet;
        const float i11 = (a * i9 - c * c) * rdet;
        const float i12 = (c * b - a * f) * rdet;
        const float i22 = (a * e - b * b) * rdet;

#pragma unroll
        for (int k = 0; k < 7; ++k) {
            // u = wsum_k - SUMM_k * v   (merges term2 and r_og@jacob_tw)
            const float ux = wx[k] - SUMM[k] * vx;
            const float uy = wy[k] - SUMM[k] * vy;
            const float uz = wz[k] - SUMM[k] * vz;
            const float jx = jt[0][k], jy = jt[1][k], jz = jt[2][k];
            // H_theta[:,k] = SI_k o rot_k + u x jt_k
            const float htx = SIX[k] * rot[0][k] + uy * jz - uz * jy;
            const float hty = SIY[k] * rot[1][k] + uz * jx - ux * jz;
            const float htz = SIZ[k] * rot[2][k] + ux * jy - uy * jx;
            // b = H_inv @ H_theta[:,k]
            const float bx = i00 * htx + i01 * hty + i02 * htz;
            const float by = i01 * htx + i11 * hty + i12 * htz;
            const float bz = i02 * htx + i12 * hty + i22 * htz;
            const float s = SUMM[k] * INV_TM;  // jacob_tw/TM = s * jt
            o[0 * 7 + k] = -(s * jx + vy * bz - vz * by);
            o[1 * 7 + k] = -(s * jy + vz * bx - vx * bz);
            o[2 * 7 + k] = -(s * jz + vx * by - vy * bx);
            o[3 * 7 + k] = -bx;
            o[4 * 7 + k] = -by;
            o[5 * 7 + k] = -bz;
        }
    } else {
        // bm == 0: del_p = trans[:,7] - trans[:,k]; out = [rot x del_p ; rot]
#pragma unroll
        for (int k = 0; k < 7; ++k) {
            const float dx = tr[0][7] - tr[0][k];
            const float dy = tr[1][7] - tr[1][k];
            const float dz = tr[2][7] - tr[2][k];
            o[0 * 7 + k] = rot[1][k] * dz - rot[2][k] * dy;
            o[1 * 7 + k] = rot[2][k] * dx - rot[0][k] * dz;
            o[2 * 7 + k] = rot[0][k] * dy - rot[1][k] * dx;
            o[3 * 7 + k] = rot[0][k];
            o[4 * 7 + k] = rot[1][k];
            o[5 * 7 + k] = rot[2][k];
        }
    }

    // ---- store 42 floats as 21 float2 (8B-aligned: 42*4=168, 168%8==0) ----
    float2* Ob = reinterpret_cast<float2*>(out + (size_t)idx * 42);
#pragma unroll
    for (int t = 0; t < 21; ++t) Ob[t] = make_float2(o[2 * t], o[2 * t + 1]);
}

extern "C" void kernel_launch(void* const* d_in, const int* in_sizes, int n_in,
                              void* d_out, int out_size, void* d_ws, size_t ws_size,
                              hipStream_t stream) {
    const float* com  = (const float*)d_in[0];   // (512,256,3,7)  f32
    const float* pose = (const float*)d_in[1];   // (512,256,4,4,9) f32
    const int*   bm   = (const int*)d_in[2];     // scalar
    float* out = (float*)d_out;                  // (512,256,6,7)  f32

    const int n_items = in_sizes[0] / 21;        // 131072
    const int block = 256;
    const int grid = (n_items + block - 1) / block;
    canadarm_jacob_kernel<<<grid, block, 0, stream>>>(com, pose, bm, out, n_items);
}